// Round 3
// baseline (1043.795 us; speedup 1.0000x reference)
//
#include <hip/hip_runtime.h>
#include <stdint.h>

#define BB 4096
#define TT 200
#define DD 128
#define HH 128

typedef __attribute__((ext_vector_type(8))) short bf16x8;
typedef __attribute__((ext_vector_type(4))) float f32x4;

__device__ __forceinline__ short f2bf(float f) {
    uint32_t u = __builtin_bit_cast(uint32_t, f);
    u += 0x7fffu + ((u >> 16) & 1u);   // RNE
    return (short)(u >> 16);
}
__device__ __forceinline__ uint32_t pk2(float a, float b) {
    uint32_t r;
    asm("v_cvt_pk_bf16_f32 %0, %1, %2" : "=v"(r) : "v"(a), "v"(b));
    return r;
}
__device__ __forceinline__ float sigm(float x) {
    return __builtin_amdgcn_rcpf(1.0f + __expf(-x));
}
__device__ __forceinline__ float tanhf_(float x) {
    return 2.0f * __builtin_amdgcn_rcpf(1.0f + __expf(-2.0f * x)) - 1.0f;
}
// LDS-only barrier: drain lgkm (our ds ops), NOT vmcnt -> global prefetch
// stays in flight across the barrier.
__device__ __forceinline__ void bar_lds() {
    asm volatile("s_waitcnt lgkmcnt(0)" ::: "memory");
    __builtin_amdgcn_sched_barrier(0);
    __builtin_amdgcn_s_barrier();
    __builtin_amdgcn_sched_barrier(0);
}

// Round-3 structure: 8 batch rows/block, 512 blocks -> 2 co-resident blocks/CU
// with INDEPENDENT barriers (theory: barrier-convoy latency bound; lockstep
// waves in one block overlap identical stalls, out-of-phase blocks fill them).
// MFMA B-operand rows 8-15 duplicate rows 0-7 (reads via c&7, stores masked).
// VGPR must stay <=256 for 2 waves/SIMD: __launch_bounds__(256,2).
//
// LDS: [8 rows][16 granules] of bf16x8, granule XOR-swizzled by row.

#define STEP(T, XR) { \
    const int sn_ = ((T) + 1) & 1; \
    *(uint2*)((short*)&xbuf[sn_][xrow][xg_swz] + xhalf) = \
        make_uint2(pk2(XR.x, XR.y), pk2(XR.z, XR.w)); \
    { const int t3_ = ((T) + 3 < TT) ? (T) + 3 : TT - 1; \
      XR = *(const float4*)(xsrc + (size_t)t3_ * DD); } \
    bf16x8 hf_[4]; \
    _Pragma("unroll") \
    for (int kt = 0; kt < 4; ++kt) hf_[kt] = hrow[fg[kt]]; \
    f32x4 az_[2], ar_[2]; \
    _Pragma("unroll") \
    for (int ct = 0; ct < 2; ++ct) { az_[ct] = pz[ct]; ar_[ct] = pr[ct]; } \
    _Pragma("unroll") \
    for (int kt = 0; kt < 4; ++kt) { \
        _Pragma("unroll") \
        for (int ct = 0; ct < 2; ++ct) { \
            az_[ct] = __builtin_amdgcn_mfma_f32_16x16x32_bf16(Wf[0][1][kt][ct], hf_[kt], az_[ct], 0, 0, 0); \
            ar_[ct] = __builtin_amdgcn_mfma_f32_16x16x32_bf16(Wf[1][1][kt][ct], hf_[kt], ar_[ct], 0, 0, 0); \
        } \
    } \
    f32x4 zv_[2], rhv_[2]; \
    _Pragma("unroll") \
    for (int ct = 0; ct < 2; ++ct) { \
        _Pragma("unroll") \
        for (int r = 0; r < 4; ++r) { \
            zv_[ct][r]  = sigm(az_[ct][r]); \
            rhv_[ct][r] = sigm(ar_[ct][r]) * hreg[ct][r]; \
        } \
        if (valid) \
            *(uint2*)((short*)&rhbuf[cr][gout[ct]] + ohalf) = \
                make_uint2(pk2(rhv_[ct][0], rhv_[ct][1]), pk2(rhv_[ct][2], rhv_[ct][3])); \
    } \
    bar_lds(); \
    const float a_c_ = attbuf[cr][(T)]; \
    bf16x8 rf_[4], xf2_[4]; \
    { const bf16x8* xp2_ = &xbuf[sn_][cr][0]; \
      _Pragma("unroll") \
      for (int kt = 0; kt < 4; ++kt) { \
          rf_[kt]  = rhrow[fg[kt]]; \
          xf2_[kt] = xp2_[fg[kt]]; \
      } } \
    f32x4 ah_[2]; \
    _Pragma("unroll") \
    for (int ct = 0; ct < 2; ++ct) ah_[ct] = ph[ct]; \
    _Pragma("unroll") \
    for (int kt = 0; kt < 4; ++kt) { \
        _Pragma("unroll") \
        for (int ct = 0; ct < 2; ++ct) \
            ah_[ct] = __builtin_amdgcn_mfma_f32_16x16x32_bf16(Wf[2][1][kt][ct], rf_[kt], ah_[ct], 0, 0, 0); \
    } \
    _Pragma("unroll") \
    for (int ct = 0; ct < 2; ++ct) { pz[ct] = bzv[ct]; pr[ct] = brv[ct]; ph[ct] = bhv[ct]; } \
    _Pragma("unroll") \
    for (int kt = 0; kt < 4; ++kt) { \
        _Pragma("unroll") \
        for (int ct = 0; ct < 2; ++ct) { \
            pz[ct] = __builtin_amdgcn_mfma_f32_16x16x32_bf16(Wf[0][0][kt][ct], xf2_[kt], pz[ct], 0, 0, 0); \
            pr[ct] = __builtin_amdgcn_mfma_f32_16x16x32_bf16(Wf[1][0][kt][ct], xf2_[kt], pr[ct], 0, 0, 0); \
            ph[ct] = __builtin_amdgcn_mfma_f32_16x16x32_bf16(Wf[2][0][kt][ct], xf2_[kt], ph[ct], 0, 0, 0); \
        } \
    } \
    _Pragma("unroll") \
    for (int ct = 0; ct < 2; ++ct) { \
        _Pragma("unroll") \
        for (int r = 0; r < 4; ++r) { \
            float ht_ = tanhf_(ah_[ct][r]); \
            float zp_ = a_c_ * zv_[ct][r]; \
            hreg[ct][r] = __builtin_fmaf(zp_, ht_ - hreg[ct][r], hreg[ct][r]); \
        } \
        if (valid) \
            *(uint2*)((short*)&hbuf[cr][gout[ct]] + ohalf) = \
                make_uint2(pk2(hreg[ct][0], hreg[ct][1]), pk2(hreg[ct][2], hreg[ct][3])); \
    } \
    bar_lds(); \
}

__global__ __launch_bounds__(256, 2) void augru_kernel(
    const float* __restrict__ inp,   // [B,T,D]
    const float* __restrict__ att,   // [B,T]
    const float* __restrict__ h0,    // [B,H]
    const float* __restrict__ Wz, const float* __restrict__ bz,
    const float* __restrict__ Wr, const float* __restrict__ br,
    const float* __restrict__ Wh, const float* __restrict__ bh,
    float* __restrict__ out)         // [B,H]
{
    __shared__ bf16x8 xbuf[2][8][16];    // x(t) bf16, swizzled granules
    __shared__ bf16x8 hbuf[8][16];       // h(t) bf16 mirror, swizzled
    __shared__ bf16x8 rhbuf[8][16];      // r*h staging, swizzled
    __shared__ float attbuf[8][201];     // whole att tile, padded

    const int tid  = threadIdx.x;
    const int wave = tid >> 6;           // 0..3
    const int lane = tid & 63;
    const int c    = lane & 15;          // MFMA B-row slot (8-15 mirror 0-7)
    const int cr   = c & 7;              // real batch row
    const bool valid = (c < 8);
    const int grp  = lane >> 4;          // k-group
    const int wbase = wave * 32;         // this wave's 32 output cols
    const int rowbase = blockIdx.x * 8;

    // swizzle constants (loop-invariant)
    const int swz = cr;
    const int fg[4] = { (0 + grp) ^ swz, (4 + grp) ^ swz,
                        (8 + grp) ^ swz, (12 + grp) ^ swz };
    const int oc[2]   = { wbase + grp * 4, wbase + 16 + grp * 4 };
    const int gout[2] = { (4 * wave + (grp >> 1)) ^ swz,
                          (4 * wave + 2 + (grp >> 1)) ^ swz };
    const int ohalf = (grp & 1) * 4;     // short offset within granule
    const bf16x8* hrow  = &hbuf[cr][0];
    const bf16x8* rhrow = &rhbuf[cr][0];

    // ---------------- weights -> register fragments ----------------
    bf16x8 Wf[3][2][4][2];
    {
        const float* Wp[3] = {Wz, Wr, Wh};
        #pragma unroll
        for (int g3 = 0; g3 < 3; ++g3) {
            #pragma unroll
            for (int p = 0; p < 2; ++p) {
                #pragma unroll
                for (int kt = 0; kt < 4; ++kt) {
                    #pragma unroll
                    for (int ct = 0; ct < 2; ++ct) {
                        bf16x8 v;
                        #pragma unroll
                        for (int j = 0; j < 8; ++j) {
                            int k = p * 128 + kt * 32 + grp * 8 + j;
                            v[j] = f2bf(Wp[g3][(size_t)k * HH + wbase + ct * 16 + c]);
                        }
                        Wf[g3][p][kt][ct] = v;
                    }
                }
            }
        }
    }
    f32x4 bzv[2], brv[2], bhv[2];
    #pragma unroll
    for (int ct = 0; ct < 2; ++ct)
        #pragma unroll
        for (int r = 0; r < 4; ++r) {
            bzv[ct][r] = bz[oc[ct] + r];
            brv[ct][r] = br[oc[ct] + r];
            bhv[ct][r] = bh[oc[ct] + r];
        }

    // ---------------- att tile -> LDS (one-time, coalesced) ----------------
    for (int idx = tid; idx < 8 * TT; idx += 256)
        attbuf[idx / TT][idx % TT] = att[(size_t)rowbase * TT + idx];

    // ---------------- h state (duplicate rows for c>=8) ----------------
    f32x4 hreg[2];
    #pragma unroll
    for (int ct = 0; ct < 2; ++ct) {
        float4 hv = *(const float4*)&h0[(size_t)(rowbase + cr) * HH + oc[ct]];
        hreg[ct][0] = hv.x; hreg[ct][1] = hv.y; hreg[ct][2] = hv.z; hreg[ct][3] = hv.w;
        if (valid)
            *(uint2*)((short*)&hbuf[cr][gout[ct]] + ohalf) =
                make_uint2(pk2(hv.x, hv.y), pk2(hv.z, hv.w));
    }

    // ---------------- x(0) stage; prefetch x(1), x(2) ----------------
    // 256 threads stage 8 rows x 128 cols: one float4 per thread per t.
    const int xrow = tid >> 5;            // 0..7
    const int xc4  = (tid & 31) * 4;
    const int xg_swz = ((tid & 31) >> 1) ^ xrow;   // granule of xc4, swizzled
    const int xhalf  = (tid & 1) * 4;
    const float* xsrc = inp + ((size_t)(rowbase + xrow) * TT) * DD + xc4;
    {
        float4 x0 = *(const float4*)(xsrc);
        *(uint2*)((short*)&xbuf[0][xrow][xg_swz] + xhalf) =
            make_uint2(pk2(x0.x, x0.y), pk2(x0.z, x0.w));
    }
    float4 xrA = *(const float4*)(xsrc + DD);
    float4 xrB = *(const float4*)(xsrc + 2 * DD);
    __syncthreads();

    // pre(0): feed-forward x-parts
    f32x4 pz[2], pr[2], ph[2];
    #pragma unroll
    for (int ct = 0; ct < 2; ++ct) { pz[ct] = bzv[ct]; pr[ct] = brv[ct]; ph[ct] = bhv[ct]; }
    {
        const bf16x8* x0p = &xbuf[0][cr][0];
        bf16x8 xf[4];
        #pragma unroll
        for (int kt = 0; kt < 4; ++kt) xf[kt] = x0p[fg[kt]];
        #pragma unroll
        for (int kt = 0; kt < 4; ++kt) {
            #pragma unroll
            for (int ct = 0; ct < 2; ++ct) {
                pz[ct] = __builtin_amdgcn_mfma_f32_16x16x32_bf16(Wf[0][0][kt][ct], xf[kt], pz[ct], 0, 0, 0);
                pr[ct] = __builtin_amdgcn_mfma_f32_16x16x32_bf16(Wf[1][0][kt][ct], xf[kt], pr[ct], 0, 0, 0);
                ph[ct] = __builtin_amdgcn_mfma_f32_16x16x32_bf16(Wf[2][0][kt][ct], xf[kt], ph[ct], 0, 0, 0);
            }
        }
    }

    // ---------------- scan (unrolled x2: xrA even steps, xrB odd) ----------------
    for (int t = 0; t < TT; t += 2) {
        STEP(t, xrA);
        STEP(t + 1, xrB);
    }

    // ---------------- store h_final (valid rows only) ----------------
    if (valid) {
        #pragma unroll
        for (int ct = 0; ct < 2; ++ct) {
            float4 o; o.x = hreg[ct][0]; o.y = hreg[ct][1]; o.z = hreg[ct][2]; o.w = hreg[ct][3];
            *(float4*)&out[(size_t)(rowbase + cr) * HH + oc[ct]] = o;
        }
    }
}

extern "C" void kernel_launch(void* const* d_in, const int* in_sizes, int n_in,
                              void* d_out, int out_size, void* d_ws, size_t ws_size,
                              hipStream_t stream) {
    const float* inp = (const float*)d_in[0];
    const float* att = (const float*)d_in[1];
    const float* h0  = (const float*)d_in[2];
    const float* Wz  = (const float*)d_in[3];
    const float* bz  = (const float*)d_in[4];
    const float* Wr  = (const float*)d_in[5];
    const float* br  = (const float*)d_in[6];
    const float* Wh  = (const float*)d_in[7];
    const float* bh  = (const float*)d_in[8];
    float* out = (float*)d_out;

    dim3 grid(BB / 8), block(256);
    augru_kernel<<<grid, block, 0, stream>>>(inp, att, h0, Wz, bz, Wr, br, Wh, bh, out);
}

// Round 4
// 418.953 us; speedup vs baseline: 2.4914x; 2.4914x over previous
//
#include <hip/hip_runtime.h>
#include <stdint.h>

#define BB 4096
#define TT 200
#define DD 128
#define HH 128

typedef __attribute__((ext_vector_type(8))) short bf16x8;
typedef __attribute__((ext_vector_type(4))) float f32x4;

__device__ __forceinline__ short f2bf(float f) {
    uint32_t u = __builtin_bit_cast(uint32_t, f);
    u += 0x7fffu + ((u >> 16) & 1u);   // RNE
    return (short)(u >> 16);
}
__device__ __forceinline__ uint32_t pk2(float a, float b) {
    uint32_t r;
    asm("v_cvt_pk_bf16_f32 %0, %1, %2" : "=v"(r) : "v"(a), "v"(b));
    return r;
}
__device__ __forceinline__ float sigm(float x) {
    return __builtin_amdgcn_rcpf(1.0f + __expf(-x));
}
__device__ __forceinline__ float tanhf_(float x) {
    return 2.0f * __builtin_amdgcn_rcpf(1.0f + __expf(-2.0f * x)) - 1.0f;
}
// LDS-only barrier: drain lgkm (our ds ops), NOT vmcnt -> global prefetch
// stays in flight across the barrier.
__device__ __forceinline__ void bar_lds() {
    asm volatile("s_waitcnt lgkmcnt(0)" ::: "memory");
    __builtin_amdgcn_sched_barrier(0);
    __builtin_amdgcn_s_barrier();
    __builtin_amdgcn_sched_barrier(0);
}

// Round-4: 8 batch rows/block, 512 blocks -> 2 co-resident blocks/CU with
// INDEPENDENT barriers (theory: barrier-convoy latency bound). Round 3 tested
// this with __launch_bounds__(256,2), which made the backend cap VGPR at 128
// and spill ~1.1GB to scratch (FETCH 1.5GB, 5x regression). Fix: (256,1) and
// rely on natural ~252-VGPR allocation (2x252 <= 512/SIMD) for 2-block
// residency. MFMA B-operand rows 8-15 duplicate rows 0-7 (reads via c&7,
// stores masked).
//
// LDS: [8 rows][16 granules] of bf16x8, granule XOR-swizzled by row.

#define STEP(T, XR) { \
    const int sn_ = ((T) + 1) & 1; \
    *(uint2*)((short*)&xbuf[sn_][xrow][xg_swz] + xhalf) = \
        make_uint2(pk2(XR.x, XR.y), pk2(XR.z, XR.w)); \
    { const int t3_ = ((T) + 3 < TT) ? (T) + 3 : TT - 1; \
      XR = *(const float4*)(xsrc + (size_t)t3_ * DD); } \
    bf16x8 hf_[4]; \
    _Pragma("unroll") \
    for (int kt = 0; kt < 4; ++kt) hf_[kt] = hrow[fg[kt]]; \
    f32x4 az_[2], ar_[2]; \
    _Pragma("unroll") \
    for (int ct = 0; ct < 2; ++ct) { az_[ct] = pz[ct]; ar_[ct] = pr[ct]; } \
    _Pragma("unroll") \
    for (int kt = 0; kt < 4; ++kt) { \
        _Pragma("unroll") \
        for (int ct = 0; ct < 2; ++ct) { \
            az_[ct] = __builtin_amdgcn_mfma_f32_16x16x32_bf16(Wf[0][1][kt][ct], hf_[kt], az_[ct], 0, 0, 0); \
            ar_[ct] = __builtin_amdgcn_mfma_f32_16x16x32_bf16(Wf[1][1][kt][ct], hf_[kt], ar_[ct], 0, 0, 0); \
        } \
    } \
    f32x4 zv_[2], rhv_[2]; \
    _Pragma("unroll") \
    for (int ct = 0; ct < 2; ++ct) { \
        _Pragma("unroll") \
        for (int r = 0; r < 4; ++r) { \
            zv_[ct][r]  = sigm(az_[ct][r]); \
            rhv_[ct][r] = sigm(ar_[ct][r]) * hreg[ct][r]; \
        } \
        if (valid) \
            *(uint2*)((short*)&rhbuf[cr][gout[ct]] + ohalf) = \
                make_uint2(pk2(rhv_[ct][0], rhv_[ct][1]), pk2(rhv_[ct][2], rhv_[ct][3])); \
    } \
    bar_lds(); \
    const float a_c_ = attbuf[cr][(T)]; \
    bf16x8 rf_[4], xf2_[4]; \
    { const bf16x8* xp2_ = &xbuf[sn_][cr][0]; \
      _Pragma("unroll") \
      for (int kt = 0; kt < 4; ++kt) { \
          rf_[kt]  = rhrow[fg[kt]]; \
          xf2_[kt] = xp2_[fg[kt]]; \
      } } \
    f32x4 ah_[2]; \
    _Pragma("unroll") \
    for (int ct = 0; ct < 2; ++ct) ah_[ct] = ph[ct]; \
    _Pragma("unroll") \
    for (int kt = 0; kt < 4; ++kt) { \
        _Pragma("unroll") \
        for (int ct = 0; ct < 2; ++ct) \
            ah_[ct] = __builtin_amdgcn_mfma_f32_16x16x32_bf16(Wf[2][1][kt][ct], rf_[kt], ah_[ct], 0, 0, 0); \
    } \
    _Pragma("unroll") \
    for (int ct = 0; ct < 2; ++ct) { pz[ct] = bzv[ct]; pr[ct] = brv[ct]; ph[ct] = bhv[ct]; } \
    _Pragma("unroll") \
    for (int kt = 0; kt < 4; ++kt) { \
        _Pragma("unroll") \
        for (int ct = 0; ct < 2; ++ct) { \
            pz[ct] = __builtin_amdgcn_mfma_f32_16x16x32_bf16(Wf[0][0][kt][ct], xf2_[kt], pz[ct], 0, 0, 0); \
            pr[ct] = __builtin_amdgcn_mfma_f32_16x16x32_bf16(Wf[1][0][kt][ct], xf2_[kt], pr[ct], 0, 0, 0); \
            ph[ct] = __builtin_amdgcn_mfma_f32_16x16x32_bf16(Wf[2][0][kt][ct], xf2_[kt], ph[ct], 0, 0, 0); \
        } \
    } \
    _Pragma("unroll") \
    for (int ct = 0; ct < 2; ++ct) { \
        _Pragma("unroll") \
        for (int r = 0; r < 4; ++r) { \
            float ht_ = tanhf_(ah_[ct][r]); \
            float zp_ = a_c_ * zv_[ct][r]; \
            hreg[ct][r] = __builtin_fmaf(zp_, ht_ - hreg[ct][r], hreg[ct][r]); \
        } \
        if (valid) \
            *(uint2*)((short*)&hbuf[cr][gout[ct]] + ohalf) = \
                make_uint2(pk2(hreg[ct][0], hreg[ct][1]), pk2(hreg[ct][2], hreg[ct][3])); \
    } \
    bar_lds(); \
}

__global__ __launch_bounds__(256, 1) void augru_kernel(
    const float* __restrict__ inp,   // [B,T,D]
    const float* __restrict__ att,   // [B,T]
    const float* __restrict__ h0,    // [B,H]
    const float* __restrict__ Wz, const float* __restrict__ bz,
    const float* __restrict__ Wr, const float* __restrict__ br,
    const float* __restrict__ Wh, const float* __restrict__ bh,
    float* __restrict__ out)         // [B,H]
{
    __shared__ bf16x8 xbuf[2][8][16];    // x(t) bf16, swizzled granules
    __shared__ bf16x8 hbuf[8][16];       // h(t) bf16 mirror, swizzled
    __shared__ bf16x8 rhbuf[8][16];      // r*h staging, swizzled
    __shared__ float attbuf[8][201];     // whole att tile, padded

    const int tid  = threadIdx.x;
    const int wave = tid >> 6;           // 0..3
    const int lane = tid & 63;
    const int c    = lane & 15;          // MFMA B-row slot (8-15 mirror 0-7)
    const int cr   = c & 7;              // real batch row
    const bool valid = (c < 8);
    const int grp  = lane >> 4;          // k-group
    const int wbase = wave * 32;         // this wave's 32 output cols
    const int rowbase = blockIdx.x * 8;

    // swizzle constants (loop-invariant)
    const int swz = cr;
    const int fg[4] = { (0 + grp) ^ swz, (4 + grp) ^ swz,
                        (8 + grp) ^ swz, (12 + grp) ^ swz };
    const int oc[2]   = { wbase + grp * 4, wbase + 16 + grp * 4 };
    const int gout[2] = { (4 * wave + (grp >> 1)) ^ swz,
                          (4 * wave + 2 + (grp >> 1)) ^ swz };
    const int ohalf = (grp & 1) * 4;     // short offset within granule
    const bf16x8* hrow  = &hbuf[cr][0];
    const bf16x8* rhrow = &rhbuf[cr][0];

    // ---------------- weights -> register fragments ----------------
    bf16x8 Wf[3][2][4][2];
    {
        const float* Wp[3] = {Wz, Wr, Wh};
        #pragma unroll
        for (int g3 = 0; g3 < 3; ++g3) {
            #pragma unroll
            for (int p = 0; p < 2; ++p) {
                #pragma unroll
                for (int kt = 0; kt < 4; ++kt) {
                    #pragma unroll
                    for (int ct = 0; ct < 2; ++ct) {
                        bf16x8 v;
                        #pragma unroll
                        for (int j = 0; j < 8; ++j) {
                            int k = p * 128 + kt * 32 + grp * 8 + j;
                            v[j] = f2bf(Wp[g3][(size_t)k * HH + wbase + ct * 16 + c]);
                        }
                        Wf[g3][p][kt][ct] = v;
                    }
                }
            }
        }
    }
    f32x4 bzv[2], brv[2], bhv[2];
    #pragma unroll
    for (int ct = 0; ct < 2; ++ct)
        #pragma unroll
        for (int r = 0; r < 4; ++r) {
            bzv[ct][r] = bz[oc[ct] + r];
            brv[ct][r] = br[oc[ct] + r];
            bhv[ct][r] = bh[oc[ct] + r];
        }

    // ---------------- att tile -> LDS (one-time, coalesced) ----------------
    for (int idx = tid; idx < 8 * TT; idx += 256)
        attbuf[idx / TT][idx % TT] = att[(size_t)rowbase * TT + idx];

    // ---------------- h state (duplicate rows for c>=8) ----------------
    f32x4 hreg[2];
    #pragma unroll
    for (int ct = 0; ct < 2; ++ct) {
        float4 hv = *(const float4*)&h0[(size_t)(rowbase + cr) * HH + oc[ct]];
        hreg[ct][0] = hv.x; hreg[ct][1] = hv.y; hreg[ct][2] = hv.z; hreg[ct][3] = hv.w;
        if (valid)
            *(uint2*)((short*)&hbuf[cr][gout[ct]] + ohalf) =
                make_uint2(pk2(hv.x, hv.y), pk2(hv.z, hv.w));
    }

    // ---------------- x(0) stage; prefetch x(1), x(2) ----------------
    // 256 threads stage 8 rows x 128 cols: one float4 per thread per t.
    const int xrow = tid >> 5;            // 0..7
    const int xc4  = (tid & 31) * 4;
    const int xg_swz = ((tid & 31) >> 1) ^ xrow;   // granule of xc4, swizzled
    const int xhalf  = (tid & 1) * 4;
    const float* xsrc = inp + ((size_t)(rowbase + xrow) * TT) * DD + xc4;
    {
        float4 x0 = *(const float4*)(xsrc);
        *(uint2*)((short*)&xbuf[0][xrow][xg_swz] + xhalf) =
            make_uint2(pk2(x0.x, x0.y), pk2(x0.z, x0.w));
    }
    float4 xrA = *(const float4*)(xsrc + DD);
    float4 xrB = *(const float4*)(xsrc + 2 * DD);
    __syncthreads();

    // pre(0): feed-forward x-parts
    f32x4 pz[2], pr[2], ph[2];
    #pragma unroll
    for (int ct = 0; ct < 2; ++ct) { pz[ct] = bzv[ct]; pr[ct] = brv[ct]; ph[ct] = bhv[ct]; }
    {
        const bf16x8* x0p = &xbuf[0][cr][0];
        bf16x8 xf[4];
        #pragma unroll
        for (int kt = 0; kt < 4; ++kt) xf[kt] = x0p[fg[kt]];
        #pragma unroll
        for (int kt = 0; kt < 4; ++kt) {
            #pragma unroll
            for (int ct = 0; ct < 2; ++ct) {
                pz[ct] = __builtin_amdgcn_mfma_f32_16x16x32_bf16(Wf[0][0][kt][ct], xf[kt], pz[ct], 0, 0, 0);
                pr[ct] = __builtin_amdgcn_mfma_f32_16x16x32_bf16(Wf[1][0][kt][ct], xf[kt], pr[ct], 0, 0, 0);
                ph[ct] = __builtin_amdgcn_mfma_f32_16x16x32_bf16(Wf[2][0][kt][ct], xf[kt], ph[ct], 0, 0, 0);
            }
        }
    }

    // ---------------- scan (unrolled x2: xrA even steps, xrB odd) ----------------
    for (int t = 0; t < TT; t += 2) {
        STEP(t, xrA);
        STEP(t + 1, xrB);
    }

    // ---------------- store h_final (valid rows only) ----------------
    if (valid) {
        #pragma unroll
        for (int ct = 0; ct < 2; ++ct) {
            float4 o; o.x = hreg[ct][0]; o.y = hreg[ct][1]; o.z = hreg[ct][2]; o.w = hreg[ct][3];
            *(float4*)&out[(size_t)(rowbase + cr) * HH + oc[ct]] = o;
        }
    }
}

extern "C" void kernel_launch(void* const* d_in, const int* in_sizes, int n_in,
                              void* d_out, int out_size, void* d_ws, size_t ws_size,
                              hipStream_t stream) {
    const float* inp = (const float*)d_in[0];
    const float* att = (const float*)d_in[1];
    const float* h0  = (const float*)d_in[2];
    const float* Wz  = (const float*)d_in[3];
    const float* bz  = (const float*)d_in[4];
    const float* Wr  = (const float*)d_in[5];
    const float* br  = (const float*)d_in[6];
    const float* Wh  = (const float*)d_in[7];
    const float* bh  = (const float*)d_in[8];
    float* out = (float*)d_out;

    dim3 grid(BB / 8), block(256);
    augru_kernel<<<grid, block, 0, stream>>>(inp, att, h0, Wz, bz, Wr, br, Wh, bh, out);
}

// Round 5
// 227.561 us; speedup vs baseline: 4.5869x; 1.8411x over previous
//
#include <hip/hip_runtime.h>
#include <stdint.h>

#define BB 4096
#define TT 200
#define DD 128
#define HH 128

typedef __attribute__((ext_vector_type(8))) short bf16x8;
typedef __attribute__((ext_vector_type(4))) float f32x4;

__device__ __forceinline__ short f2bf(float f) {
    uint32_t u = __builtin_bit_cast(uint32_t, f);
    u += 0x7fffu + ((u >> 16) & 1u);   // RNE
    return (short)(u >> 16);
}
__device__ __forceinline__ uint32_t pk2(float a, float b) {
    uint32_t r;
    asm("v_cvt_pk_bf16_f32 %0, %1, %2" : "=v"(r) : "v"(a), "v"(b));
    return r;
}
__device__ __forceinline__ float sigm(float x) {
    return __builtin_amdgcn_rcpf(1.0f + __expf(-x));
}
__device__ __forceinline__ float tanhf_(float x) {
    return 2.0f * __builtin_amdgcn_rcpf(1.0f + __expf(-2.0f * x)) - 1.0f;
}
// LDS-only barrier: drain lgkm (our ds ops), NOT vmcnt -> global prefetch
// stays in flight across the barrier.
__device__ __forceinline__ void bar_lds() {
    asm volatile("s_waitcnt lgkmcnt(0)" ::: "memory");
    __builtin_amdgcn_sched_barrier(0);
    __builtin_amdgcn_s_barrier();
    __builtin_amdgcn_sched_barrier(0);
}

// Round-5: back to 16 rows/block, 256 blocks, 4 waves x 32 cols (the 216us
// structure). Rocprof showed ~65% stall, latency-bound on the serial chain
// with 1 wave/SIMD. Changes target exposed latency:
//  (1) recurrent MFMA chains split 4-deep -> 2x2-deep parallel accumulators
//      (+final v_add): saves ~2 dep-hops x ~31cyc x 3 chains per step.
//  (2) x staged 2 steps ahead: the x-fragment ds_reads for phase B's
//      feed-forward MFMAs move into phase A (overlap z/r chain); phase B
//      starts with only rf_ reads.
//  (3) phase A issues ds_reads BEFORE the stage ds_write (lgkm completes
//      in-order; write needs vmcnt on the global prefetch).
//
// LDS: [16 rows][16 granules] of bf16x8, granule XOR-swizzled by (row&7);
// fragment reads are conflict-free ds_read_b128.

#define STEP(T, XR0, XR1) { \
    /* ---- phase A: ds reads first ---- */ \
    bf16x8 hf_[4]; \
    _Pragma("unroll") \
    for (int kt = 0; kt < 4; ++kt) hf_[kt] = hrow[fg[kt]]; \
    bf16x8 xf2_[4]; \
    { const bf16x8* xp_ = &xbuf[((T) + 1) & 1][c][0]; \
      _Pragma("unroll") \
      for (int kt = 0; kt < 4; ++kt) xf2_[kt] = xp_[fg[kt]]; } \
    const float a_c_ = attbuf[c][(T)]; \
    /* z/r: 2+2 parallel accumulator chains */ \
    f32x4 azA_[2], azB_[2], arA_[2], arB_[2]; \
    _Pragma("unroll") \
    for (int ct = 0; ct < 2; ++ct) { \
        azA_[ct] = pz[ct]; arA_[ct] = pr[ct]; \
        azB_[ct] = zzero;  arB_[ct] = zzero; \
    } \
    _Pragma("unroll") \
    for (int kt = 0; kt < 2; ++kt) { \
        _Pragma("unroll") \
        for (int ct = 0; ct < 2; ++ct) { \
            azA_[ct] = __builtin_amdgcn_mfma_f32_16x16x32_bf16(Wf[0][1][kt][ct], hf_[kt], azA_[ct], 0, 0, 0); \
            arA_[ct] = __builtin_amdgcn_mfma_f32_16x16x32_bf16(Wf[1][1][kt][ct], hf_[kt], arA_[ct], 0, 0, 0); \
            azB_[ct] = __builtin_amdgcn_mfma_f32_16x16x32_bf16(Wf[0][1][kt + 2][ct], hf_[kt + 2], azB_[ct], 0, 0, 0); \
            arB_[ct] = __builtin_amdgcn_mfma_f32_16x16x32_bf16(Wf[1][1][kt + 2][ct], hf_[kt + 2], arB_[ct], 0, 0, 0); \
        } \
    } \
    f32x4 zv_[2], rhv_[2]; \
    _Pragma("unroll") \
    for (int ct = 0; ct < 2; ++ct) { \
        _Pragma("unroll") \
        for (int r = 0; r < 4; ++r) { \
            float az_ = azA_[ct][r] + azB_[ct][r]; \
            float ar_ = arA_[ct][r] + arB_[ct][r]; \
            zv_[ct][r]  = sigm(az_); \
            rhv_[ct][r] = sigm(ar_) * hreg[ct][r]; \
        } \
        *(uint2*)((short*)&rhbuf[c][gout[ct]] + ohalf) = \
            make_uint2(pk2(rhv_[ct][0], rhv_[ct][1]), pk2(rhv_[ct][2], rhv_[ct][3])); \
    } \
    /* stage x(T+2) -> xbuf[T&1]; reload XR = x(T+4) */ \
    *(uint4*)&xbuf[(T) & 1][xrow][xg_swz] = \
        make_uint4(pk2(XR0.x, XR0.y), pk2(XR0.z, XR0.w), \
                   pk2(XR1.x, XR1.y), pk2(XR1.z, XR1.w)); \
    { const int t4_ = ((T) + 4 < TT) ? (T) + 4 : TT - 1; \
      XR0 = *(const float4*)(xsrc + (size_t)t4_ * DD); \
      XR1 = *(const float4*)(xsrc + (size_t)t4_ * DD + 4); } \
    bar_lds(); \
    /* ---- phase B ---- */ \
    bf16x8 rf_[4]; \
    _Pragma("unroll") \
    for (int kt = 0; kt < 4; ++kt) rf_[kt] = rhrow[fg[kt]]; \
    f32x4 ahA_[2], ahB_[2]; \
    _Pragma("unroll") \
    for (int ct = 0; ct < 2; ++ct) { ahA_[ct] = ph[ct]; ahB_[ct] = zzero; } \
    _Pragma("unroll") \
    for (int kt = 0; kt < 2; ++kt) { \
        _Pragma("unroll") \
        for (int ct = 0; ct < 2; ++ct) { \
            ahA_[ct] = __builtin_amdgcn_mfma_f32_16x16x32_bf16(Wf[2][1][kt][ct], rf_[kt], ahA_[ct], 0, 0, 0); \
            ahB_[ct] = __builtin_amdgcn_mfma_f32_16x16x32_bf16(Wf[2][1][kt + 2][ct], rf_[kt + 2], ahB_[ct], 0, 0, 0); \
        } \
    } \
    _Pragma("unroll") \
    for (int ct = 0; ct < 2; ++ct) { pz[ct] = bzv[ct]; pr[ct] = brv[ct]; ph[ct] = bhv[ct]; } \
    _Pragma("unroll") \
    for (int kt = 0; kt < 4; ++kt) { \
        _Pragma("unroll") \
        for (int ct = 0; ct < 2; ++ct) { \
            pz[ct] = __builtin_amdgcn_mfma_f32_16x16x32_bf16(Wf[0][0][kt][ct], xf2_[kt], pz[ct], 0, 0, 0); \
            pr[ct] = __builtin_amdgcn_mfma_f32_16x16x32_bf16(Wf[1][0][kt][ct], xf2_[kt], pr[ct], 0, 0, 0); \
            ph[ct] = __builtin_amdgcn_mfma_f32_16x16x32_bf16(Wf[2][0][kt][ct], xf2_[kt], ph[ct], 0, 0, 0); \
        } \
    } \
    _Pragma("unroll") \
    for (int ct = 0; ct < 2; ++ct) { \
        _Pragma("unroll") \
        for (int r = 0; r < 4; ++r) { \
            float ah_ = ahA_[ct][r] + ahB_[ct][r]; \
            float ht_ = tanhf_(ah_); \
            float zp_ = a_c_ * zv_[ct][r]; \
            hreg[ct][r] = __builtin_fmaf(zp_, ht_ - hreg[ct][r], hreg[ct][r]); \
        } \
        *(uint2*)((short*)&hbuf[c][gout[ct]] + ohalf) = \
            make_uint2(pk2(hreg[ct][0], hreg[ct][1]), pk2(hreg[ct][2], hreg[ct][3])); \
    } \
    bar_lds(); \
}

__global__ __launch_bounds__(256, 1) void augru_kernel(
    const float* __restrict__ inp,   // [B,T,D]
    const float* __restrict__ att,   // [B,T]
    const float* __restrict__ h0,    // [B,H]
    const float* __restrict__ Wz, const float* __restrict__ bz,
    const float* __restrict__ Wr, const float* __restrict__ br,
    const float* __restrict__ Wh, const float* __restrict__ bh,
    float* __restrict__ out)         // [B,H]
{
    __shared__ bf16x8 xbuf[2][16][16];   // x(t) bf16, swizzled granules
    __shared__ bf16x8 hbuf[16][16];      // h(t) bf16 mirror, swizzled
    __shared__ bf16x8 rhbuf[16][16];     // r*h staging, swizzled
    __shared__ float attbuf[16][201];    // whole att tile, padded

    const int tid  = threadIdx.x;
    const int wave = tid >> 6;           // 0..3
    const int lane = tid & 63;
    const int c    = lane & 15;          // batch row
    const int grp  = lane >> 4;          // k-group
    const int wbase = wave * 32;         // this wave's 32 output cols
    const int rowbase = blockIdx.x * 16;

    const f32x4 zzero = {0.0f, 0.0f, 0.0f, 0.0f};

    // swizzle constants (loop-invariant)
    const int swz = c & 7;
    const int fg[4] = { (0 + grp) ^ swz, (4 + grp) ^ swz,
                        (8 + grp) ^ swz, (12 + grp) ^ swz };
    const int oc[2]   = { wbase + grp * 4, wbase + 16 + grp * 4 };
    const int gout[2] = { (4 * wave + (grp >> 1)) ^ swz,
                          (4 * wave + 2 + (grp >> 1)) ^ swz };
    const int ohalf = (grp & 1) * 4;     // short offset within granule
    const bf16x8* hrow  = &hbuf[c][0];
    const bf16x8* rhrow = &rhbuf[c][0];

    // ---------------- weights -> register fragments ----------------
    bf16x8 Wf[3][2][4][2];
    {
        const float* Wp[3] = {Wz, Wr, Wh};
        #pragma unroll
        for (int g3 = 0; g3 < 3; ++g3) {
            #pragma unroll
            for (int p = 0; p < 2; ++p) {
                #pragma unroll
                for (int kt = 0; kt < 4; ++kt) {
                    #pragma unroll
                    for (int ct = 0; ct < 2; ++ct) {
                        bf16x8 v;
                        #pragma unroll
                        for (int j = 0; j < 8; ++j) {
                            int k = p * 128 + kt * 32 + grp * 8 + j;
                            v[j] = f2bf(Wp[g3][(size_t)k * HH + wbase + ct * 16 + c]);
                        }
                        Wf[g3][p][kt][ct] = v;
                    }
                }
            }
        }
    }
    f32x4 bzv[2], brv[2], bhv[2];
    #pragma unroll
    for (int ct = 0; ct < 2; ++ct)
        #pragma unroll
        for (int r = 0; r < 4; ++r) {
            bzv[ct][r] = bz[oc[ct] + r];
            brv[ct][r] = br[oc[ct] + r];
            bhv[ct][r] = bh[oc[ct] + r];
        }

    // ---------------- att tile -> LDS (one-time, coalesced) ----------------
    for (int idx = tid; idx < 16 * TT; idx += 256)
        attbuf[idx / TT][idx % TT] = att[(size_t)rowbase * TT + idx];

    // ---------------- h state ----------------
    f32x4 hreg[2];
    #pragma unroll
    for (int ct = 0; ct < 2; ++ct) {
        float4 hv = *(const float4*)&h0[(size_t)(rowbase + c) * HH + oc[ct]];
        hreg[ct][0] = hv.x; hreg[ct][1] = hv.y; hreg[ct][2] = hv.z; hreg[ct][3] = hv.w;
        *(uint2*)((short*)&hbuf[c][gout[ct]] + ohalf) =
            make_uint2(pk2(hv.x, hv.y), pk2(hv.z, hv.w));
    }

    // ---------------- stage x(0),x(1); prefetch x(2),x(3) ----------------
    // thread (xrow, 8-col chunk): one bf16x8 granule per t.
    const int xrow = tid >> 4;            // 0..15
    const int xc8  = (tid & 15) * 8;      // 8-float chunk
    const int xg_swz = (tid & 15) ^ (xrow & 7);
    const float* xsrc = inp + ((size_t)(rowbase + xrow) * TT) * DD + xc8;
    {
        float4 a0 = *(const float4*)(xsrc);
        float4 a1 = *(const float4*)(xsrc + 4);
        *(uint4*)&xbuf[0][xrow][xg_swz] =
            make_uint4(pk2(a0.x, a0.y), pk2(a0.z, a0.w),
                       pk2(a1.x, a1.y), pk2(a1.z, a1.w));
        float4 b0 = *(const float4*)(xsrc + DD);
        float4 b1 = *(const float4*)(xsrc + DD + 4);
        *(uint4*)&xbuf[1][xrow][xg_swz] =
            make_uint4(pk2(b0.x, b0.y), pk2(b0.z, b0.w),
                       pk2(b1.x, b1.y), pk2(b1.z, b1.w));
    }
    float4 xrA0 = *(const float4*)(xsrc + 2 * DD);
    float4 xrA1 = *(const float4*)(xsrc + 2 * DD + 4);
    float4 xrB0 = *(const float4*)(xsrc + 3 * DD);
    float4 xrB1 = *(const float4*)(xsrc + 3 * DD + 4);
    __syncthreads();

    // pre(0): feed-forward x-parts from x(0)
    f32x4 pz[2], pr[2], ph[2];
    #pragma unroll
    for (int ct = 0; ct < 2; ++ct) { pz[ct] = bzv[ct]; pr[ct] = brv[ct]; ph[ct] = bhv[ct]; }
    {
        const bf16x8* x0p = &xbuf[0][c][0];
        bf16x8 xf[4];
        #pragma unroll
        for (int kt = 0; kt < 4; ++kt) xf[kt] = x0p[fg[kt]];
        #pragma unroll
        for (int kt = 0; kt < 4; ++kt) {
            #pragma unroll
            for (int ct = 0; ct < 2; ++ct) {
                pz[ct] = __builtin_amdgcn_mfma_f32_16x16x32_bf16(Wf[0][0][kt][ct], xf[kt], pz[ct], 0, 0, 0);
                pr[ct] = __builtin_amdgcn_mfma_f32_16x16x32_bf16(Wf[1][0][kt][ct], xf[kt], pr[ct], 0, 0, 0);
                ph[ct] = __builtin_amdgcn_mfma_f32_16x16x32_bf16(Wf[2][0][kt][ct], xf[kt], ph[ct], 0, 0, 0);
            }
        }
    }
    // protect xbuf[0] (read above) from STEP(0)'s phase-A overwrite
    __syncthreads();

    // ---------------- scan (unrolled x2) ----------------
    for (int t = 0; t < TT; t += 2) {
        STEP(t, xrA0, xrA1);
        STEP(t + 1, xrB0, xrB1);
    }

    // ---------------- store h_final ----------------
    #pragma unroll
    for (int ct = 0; ct < 2; ++ct) {
        float4 o; o.x = hreg[ct][0]; o.y = hreg[ct][1]; o.z = hreg[ct][2]; o.w = hreg[ct][3];
        *(float4*)&out[(size_t)(rowbase + c) * HH + oc[ct]] = o;
    }
}

extern "C" void kernel_launch(void* const* d_in, const int* in_sizes, int n_in,
                              void* d_out, int out_size, void* d_ws, size_t ws_size,
                              hipStream_t stream) {
    const float* inp = (const float*)d_in[0];
    const float* att = (const float*)d_in[1];
    const float* h0  = (const float*)d_in[2];
    const float* Wz  = (const float*)d_in[3];
    const float* bz  = (const float*)d_in[4];
    const float* Wr  = (const float*)d_in[5];
    const float* br  = (const float*)d_in[6];
    const float* Wh  = (const float*)d_in[7];
    const float* bh  = (const float*)d_in[8];
    float* out = (float*)d_out;

    dim3 grid(BB / 16), block(256);
    augru_kernel<<<grid, block, 0, stream>>>(inp, att, h0, Wz, bz, Wr, br, Wh, bh, out);
}

// Round 6
// 214.811 us; speedup vs baseline: 4.8591x; 1.0594x over previous
//
#include <hip/hip_runtime.h>
#include <stdint.h>

#define BB 4096
#define TT 200
#define DD 128
#define HH 128

typedef __attribute__((ext_vector_type(8))) short bf16x8;
typedef __attribute__((ext_vector_type(4))) float f32x4;

__device__ __forceinline__ short f2bf(float f) {
    uint32_t u = __builtin_bit_cast(uint32_t, f);
    u += 0x7fffu + ((u >> 16) & 1u);   // RNE
    return (short)(u >> 16);
}
__device__ __forceinline__ uint32_t pk2(float a, float b) {
    uint32_t r;
    asm("v_cvt_pk_bf16_f32 %0, %1, %2" : "=v"(r) : "v"(a), "v"(b));
    return r;
}
__device__ __forceinline__ float sigm(float x) {
    return __builtin_amdgcn_rcpf(1.0f + __expf(-x));
}
__device__ __forceinline__ float tanhf_(float x) {
    return 2.0f * __builtin_amdgcn_rcpf(1.0f + __expf(-2.0f * x)) - 1.0f;
}
// Force a vmcnt-only global load (never flat). flat_load increments BOTH
// vmcnt AND lgkmcnt (ISA §7); if the compiler picked flat for the generic
// pointer, every bar_lds lgkmcnt(0) drain would put the ~800cy HBM prefetch
// on the critical path twice per step. asm global_load_dwordx4 removes that
// possibility; consumption is guarded by an explicit vmcnt(0) one step later.
__device__ __forceinline__ float4 gload4(const float* p) {
    float4 r;
    asm volatile("global_load_dwordx4 %0, %1, off" : "=v"(r) : "v"(p));
    return r;
}
// LDS-only barrier: drain lgkm (our ds ops), NOT vmcnt -> global prefetch
// stays in flight across the barrier.
__device__ __forceinline__ void bar_lds() {
    asm volatile("s_waitcnt lgkmcnt(0)" ::: "memory");
    __builtin_amdgcn_sched_barrier(0);
    __builtin_amdgcn_s_barrier();
    __builtin_amdgcn_sched_barrier(0);
}

// Round-6: r2 structure (16 rows/block, 256 blocks, 4 waves x 32 cols,
// 4-deep accumulator chains - the 216us baseline; r5's 2x2 split accumulators
// reverted: they added 24 v_add/step for no latency win). Single change:
// in-loop x prefetch via asm global_load_dwordx4 + explicit vmcnt(0) at
// step top (satisfied ~1 step early), so lgkm drains never see it.
//
// LDS: [16 rows][16 granules] of bf16x8, granule XOR-swizzled by (row&7);
// fragment reads are conflict-free ds_read_b128.

#define STEP(T, XR0, XR1) { \
    /* XR0/XR1 were issued ~1 full step ago -> this wait is ~free */ \
    asm volatile("s_waitcnt vmcnt(0)" ::: "memory"); \
    __builtin_amdgcn_sched_barrier(0); \
    const int sn_ = ((T) + 1) & 1; \
    *(uint4*)&xbuf[sn_][xrow][xg_swz] = \
        make_uint4(pk2(XR0.x, XR0.y), pk2(XR0.z, XR0.w), \
                   pk2(XR1.x, XR1.y), pk2(XR1.z, XR1.w)); \
    { const int t3_ = ((T) + 3 < TT) ? (T) + 3 : TT - 1; \
      const float* xp_ = xsrc + (size_t)t3_ * DD; \
      XR0 = gload4(xp_); \
      XR1 = gload4(xp_ + 4); } \
    const float a_c_ = attbuf[c][(T)]; \
    bf16x8 hf_[4]; \
    _Pragma("unroll") \
    for (int kt = 0; kt < 4; ++kt) hf_[kt] = hrow[fg[kt]]; \
    f32x4 az_[2], ar_[2]; \
    _Pragma("unroll") \
    for (int ct = 0; ct < 2; ++ct) { az_[ct] = pz[ct]; ar_[ct] = pr[ct]; } \
    _Pragma("unroll") \
    for (int kt = 0; kt < 4; ++kt) { \
        _Pragma("unroll") \
        for (int ct = 0; ct < 2; ++ct) { \
            az_[ct] = __builtin_amdgcn_mfma_f32_16x16x32_bf16(Wf[0][1][kt][ct], hf_[kt], az_[ct], 0, 0, 0); \
            ar_[ct] = __builtin_amdgcn_mfma_f32_16x16x32_bf16(Wf[1][1][kt][ct], hf_[kt], ar_[ct], 0, 0, 0); \
        } \
    } \
    f32x4 zv_[2], rhv_[2]; \
    _Pragma("unroll") \
    for (int ct = 0; ct < 2; ++ct) { \
        _Pragma("unroll") \
        for (int r = 0; r < 4; ++r) { \
            zv_[ct][r]  = sigm(az_[ct][r]); \
            rhv_[ct][r] = sigm(ar_[ct][r]) * hreg[ct][r]; \
        } \
        *(uint2*)((short*)&rhbuf[c][gout[ct]] + ohalf) = \
            make_uint2(pk2(rhv_[ct][0], rhv_[ct][1]), pk2(rhv_[ct][2], rhv_[ct][3])); \
    } \
    bar_lds(); \
    bf16x8 rf_[4], xf2_[4]; \
    { const bf16x8* xp2_ = &xbuf[sn_][c][0]; \
      _Pragma("unroll") \
      for (int kt = 0; kt < 4; ++kt) { \
          rf_[kt]  = rhrow[fg[kt]]; \
          xf2_[kt] = xp2_[fg[kt]]; \
      } } \
    f32x4 ah_[2]; \
    _Pragma("unroll") \
    for (int ct = 0; ct < 2; ++ct) ah_[ct] = ph[ct]; \
    _Pragma("unroll") \
    for (int kt = 0; kt < 4; ++kt) { \
        _Pragma("unroll") \
        for (int ct = 0; ct < 2; ++ct) \
            ah_[ct] = __builtin_amdgcn_mfma_f32_16x16x32_bf16(Wf[2][1][kt][ct], rf_[kt], ah_[ct], 0, 0, 0); \
    } \
    _Pragma("unroll") \
    for (int ct = 0; ct < 2; ++ct) { pz[ct] = bzv[ct]; pr[ct] = brv[ct]; ph[ct] = bhv[ct]; } \
    _Pragma("unroll") \
    for (int kt = 0; kt < 4; ++kt) { \
        _Pragma("unroll") \
        for (int ct = 0; ct < 2; ++ct) { \
            pz[ct] = __builtin_amdgcn_mfma_f32_16x16x32_bf16(Wf[0][0][kt][ct], xf2_[kt], pz[ct], 0, 0, 0); \
            pr[ct] = __builtin_amdgcn_mfma_f32_16x16x32_bf16(Wf[1][0][kt][ct], xf2_[kt], pr[ct], 0, 0, 0); \
            ph[ct] = __builtin_amdgcn_mfma_f32_16x16x32_bf16(Wf[2][0][kt][ct], xf2_[kt], ph[ct], 0, 0, 0); \
        } \
    } \
    _Pragma("unroll") \
    for (int ct = 0; ct < 2; ++ct) { \
        _Pragma("unroll") \
        for (int r = 0; r < 4; ++r) { \
            float ht_ = tanhf_(ah_[ct][r]); \
            float zp_ = a_c_ * zv_[ct][r]; \
            hreg[ct][r] = __builtin_fmaf(zp_, ht_ - hreg[ct][r], hreg[ct][r]); \
        } \
        *(uint2*)((short*)&hbuf[c][gout[ct]] + ohalf) = \
            make_uint2(pk2(hreg[ct][0], hreg[ct][1]), pk2(hreg[ct][2], hreg[ct][3])); \
    } \
    bar_lds(); \
}

__global__ __launch_bounds__(256, 1) void augru_kernel(
    const float* __restrict__ inp,   // [B,T,D]
    const float* __restrict__ att,   // [B,T]
    const float* __restrict__ h0,    // [B,H]
    const float* __restrict__ Wz, const float* __restrict__ bz,
    const float* __restrict__ Wr, const float* __restrict__ br,
    const float* __restrict__ Wh, const float* __restrict__ bh,
    float* __restrict__ out)         // [B,H]
{
    __shared__ bf16x8 xbuf[2][16][16];   // x(t) bf16, swizzled granules
    __shared__ bf16x8 hbuf[16][16];      // h(t) bf16 mirror, swizzled
    __shared__ bf16x8 rhbuf[16][16];     // r*h staging, swizzled
    __shared__ float attbuf[16][201];    // whole att tile, padded

    const int tid  = threadIdx.x;
    const int wave = tid >> 6;           // 0..3
    const int lane = tid & 63;
    const int c    = lane & 15;          // batch row
    const int grp  = lane >> 4;          // k-group
    const int wbase = wave * 32;         // this wave's 32 output cols
    const int rowbase = blockIdx.x * 16;

    // swizzle constants (loop-invariant)
    const int swz = c & 7;
    const int fg[4] = { (0 + grp) ^ swz, (4 + grp) ^ swz,
                        (8 + grp) ^ swz, (12 + grp) ^ swz };
    const int oc[2]   = { wbase + grp * 4, wbase + 16 + grp * 4 };
    const int gout[2] = { (4 * wave + (grp >> 1)) ^ swz,
                          (4 * wave + 2 + (grp >> 1)) ^ swz };
    const int ohalf = (grp & 1) * 4;     // short offset within granule
    const bf16x8* hrow  = &hbuf[c][0];
    const bf16x8* rhrow = &rhbuf[c][0];

    // ---------------- weights -> register fragments ----------------
    bf16x8 Wf[3][2][4][2];
    {
        const float* Wp[3] = {Wz, Wr, Wh};
        #pragma unroll
        for (int g3 = 0; g3 < 3; ++g3) {
            #pragma unroll
            for (int p = 0; p < 2; ++p) {
                #pragma unroll
                for (int kt = 0; kt < 4; ++kt) {
                    #pragma unroll
                    for (int ct = 0; ct < 2; ++ct) {
                        bf16x8 v;
                        #pragma unroll
                        for (int j = 0; j < 8; ++j) {
                            int k = p * 128 + kt * 32 + grp * 8 + j;
                            v[j] = f2bf(Wp[g3][(size_t)k * HH + wbase + ct * 16 + c]);
                        }
                        Wf[g3][p][kt][ct] = v;
                    }
                }
            }
        }
    }
    f32x4 bzv[2], brv[2], bhv[2];
    #pragma unroll
    for (int ct = 0; ct < 2; ++ct)
        #pragma unroll
        for (int r = 0; r < 4; ++r) {
            bzv[ct][r] = bz[oc[ct] + r];
            brv[ct][r] = br[oc[ct] + r];
            bhv[ct][r] = bh[oc[ct] + r];
        }

    // ---------------- att tile -> LDS (one-time, coalesced) ----------------
    for (int idx = tid; idx < 16 * TT; idx += 256)
        attbuf[idx / TT][idx % TT] = att[(size_t)rowbase * TT + idx];

    // ---------------- h state ----------------
    f32x4 hreg[2];
    #pragma unroll
    for (int ct = 0; ct < 2; ++ct) {
        float4 hv = *(const float4*)&h0[(size_t)(rowbase + c) * HH + oc[ct]];
        hreg[ct][0] = hv.x; hreg[ct][1] = hv.y; hreg[ct][2] = hv.z; hreg[ct][3] = hv.w;
        *(uint2*)((short*)&hbuf[c][gout[ct]] + ohalf) =
            make_uint2(pk2(hv.x, hv.y), pk2(hv.z, hv.w));
    }

    // ---------------- x(0) stage; prefetch x(1), x(2) ----------------
    // thread (xrow, 8-col chunk): stages a full bf16x8 granule per t.
    const int xrow = tid >> 4;            // 0..15
    const int xc8  = (tid & 15) * 8;      // 8-float chunk
    const int xg_swz = (tid & 15) ^ (xrow & 7);
    const float* xsrc = inp + ((size_t)(rowbase + xrow) * TT) * DD + xc8;
    {
        float4 x0a = *(const float4*)(xsrc);
        float4 x0b = *(const float4*)(xsrc + 4);
        *(uint4*)&xbuf[0][xrow][xg_swz] =
            make_uint4(pk2(x0a.x, x0a.y), pk2(x0a.z, x0a.w),
                       pk2(x0b.x, x0b.y), pk2(x0b.z, x0b.w));
    }
    float4 xrA0 = gload4(xsrc + DD);
    float4 xrA1 = gload4(xsrc + DD + 4);
    float4 xrB0 = gload4(xsrc + 2 * DD);
    float4 xrB1 = gload4(xsrc + 2 * DD + 4);
    __syncthreads();

    // pre(0): feed-forward x-parts
    f32x4 pz[2], pr[2], ph[2];
    #pragma unroll
    for (int ct = 0; ct < 2; ++ct) { pz[ct] = bzv[ct]; pr[ct] = brv[ct]; ph[ct] = bhv[ct]; }
    {
        const bf16x8* x0p = &xbuf[0][c][0];
        bf16x8 xf[4];
        #pragma unroll
        for (int kt = 0; kt < 4; ++kt) xf[kt] = x0p[fg[kt]];
        #pragma unroll
        for (int kt = 0; kt < 4; ++kt) {
            #pragma unroll
            for (int ct = 0; ct < 2; ++ct) {
                pz[ct] = __builtin_amdgcn_mfma_f32_16x16x32_bf16(Wf[0][0][kt][ct], xf[kt], pz[ct], 0, 0, 0);
                pr[ct] = __builtin_amdgcn_mfma_f32_16x16x32_bf16(Wf[1][0][kt][ct], xf[kt], pr[ct], 0, 0, 0);
                ph[ct] = __builtin_amdgcn_mfma_f32_16x16x32_bf16(Wf[2][0][kt][ct], xf[kt], ph[ct], 0, 0, 0);
            }
        }
    }

    // ---------------- scan (unrolled x2: A regs even steps, B regs odd) ----------------
    for (int t = 0; t < TT; t += 2) {
        STEP(t, xrA0, xrA1);
        STEP(t + 1, xrB0, xrB1);
    }

    // ---------------- store h_final ----------------
    #pragma unroll
    for (int ct = 0; ct < 2; ++ct) {
        float4 o; o.x = hreg[ct][0]; o.y = hreg[ct][1]; o.z = hreg[ct][2]; o.w = hreg[ct][3];
        *(float4*)&out[(size_t)(rowbase + c) * HH + oc[ct]] = o;
    }
}

extern "C" void kernel_launch(void* const* d_in, const int* in_sizes, int n_in,
                              void* d_out, int out_size, void* d_ws, size_t ws_size,
                              hipStream_t stream) {
    const float* inp = (const float*)d_in[0];
    const float* att = (const float*)d_in[1];
    const float* h0  = (const float*)d_in[2];
    const float* Wz  = (const float*)d_in[3];
    const float* bz  = (const float*)d_in[4];
    const float* Wr  = (const float*)d_in[5];
    const float* br  = (const float*)d_in[6];
    const float* Wh  = (const float*)d_in[7];
    const float* bh  = (const float*)d_in[8];
    float* out = (float*)d_out;

    dim3 grid(BB / 16), block(256);
    augru_kernel<<<grid, block, 0, stream>>>(inp, att, h0, Wz, bz, Wr, br, Wh, bh, out);
}